// Round 13
// baseline (21.674 us; speedup 1.0000x reference)
//
#include <hip/hip_runtime.h>
#include <math.h>

// RandISH, cooperative-tile layout v4: double-buffered LDS, store||compute.
//   out[b, 2n+0] = Al(deg_n, r_b) * y0_norm[n] * P_l(ct)
//   out[b, 2n+1] = Al * cscale[n] * (-1)^deg * Re[(rx + i*ry)^deg]
// rv = vec[b] @ M[n]; rotation preserves |vec|=1 -> no normalization.
//
// Block = 512 threads = 8 waves, owns FOUR 64-direction tiles.
//   lane (0..63) = direction b         -> coalesced input loads
//   wave w (0..7) = bases n=4w..4w+3   -> deg/mats/coeffs WAVE-UNIFORM
//     (readfirstlane-forced SGPR; Re[z^d] recurrence runs deg-1 real
//      iterations, ~54% run zero).
// Two LDS buffers [64][65] (odd stride -> <=2-way banks = free), 33.3 KB
// -> 4 blocks/CU (LDS-capped) = 32 waves/CU, ALL 1024 blocks resident.
// Pipeline per phase: NT-store tile i from buf cur (issued FIRST, drains
// in background) || compute tile i+1 into buf other, then ONE barrier.
// Store chunks: consecutive threads -> consecutive 16B -> full 128B lines
// (NT full-line streaming, the fillBuffer path; R11->R12 win).
//
// Re[z^d]: R_k = 2x R_{k-1} - (x^2+y^2) R_{k-2},  R_0=1, R_1=x.
// Al = exp2(-0.5*log2e*d(d+1)*(r+eps))  (0.5/(1/(r+e)+e) ~= 0.5(r+e), 1e-8).

#define NBASIS 32
#define PLEN 10
#define EPSV 1e-8f
#define LOG2E 1.44269504088896340736f
#define ROWD 65    // LDS row stride in dwords (odd -> conflict-free)
#define NTILE 4    // tiles per block

typedef float f32x4 __attribute__((ext_vector_type(4)));

__global__ __launch_bounds__(512) void randish_kernel(
    const float* __restrict__ vec,        // (B,3)
    const float* __restrict__ rough,      // (B,)
    const float* __restrict__ mats,       // (32,3,3)
    const float* __restrict__ coeffs,     // (32,10) increasing power
    const float* __restrict__ cscale,     // (32,)
    const float* __restrict__ y0n,        // (32,)
    const int*   __restrict__ degs,       // (32,)
    float* __restrict__ out,              // (B,64)
    int B)
{
    __shared__ float lds[2][64 * ROWD];   // 33.3 KB -> 4 blocks/CU

    const int t    = threadIdx.x;         // 0..511
    const int lane = t & 63;              // direction within tile
    const int w    = t >> 6;              // wave id 0..7

    // ---- prefetch ALL tiles' inputs (independent loads, one window) ----
    float V0[NTILE], V1[NTILE], V2[NTILE], TC[NTILE];
    int   BB[NTILE];
#pragma unroll
    for (int it = 0; it < NTILE; ++it) {
        const int b0 = (blockIdx.x * NTILE + it) * 64;
        const int b  = b0 + lane;         // B % (64*NTILE) == 0 -> in range
        BB[it] = b0;
        V0[it] = vec[b * 3 + 0];
        V1[it] = vec[b * 3 + 1];
        V2[it] = vec[b * 3 + 2];
        // Al = exp2( d*(d+1) * tc ),  tc = -0.5*log2e*(r+eps)
        TC[it] = (rough[b] + EPSV) * (-0.5f * LOG2E);
    }

    // ---- compute one tile into LDS buffer `buf` ----
    auto compute_tile = [&](int it, int buf) {
        const float v0 = V0[it], v1 = V1[it], v2 = V2[it], tc = TC[it];
        float* row = &lds[buf][lane * ROWD];
#pragma unroll
        for (int j = 0; j < 4; ++j) {
            // n and all derived per-n data are wave-uniform -> SGPRs
            const int n = __builtin_amdgcn_readfirstlane(4 * w + j);
            const int d = __builtin_amdgcn_readfirstlane(degs[n]);
            const int par = d & 1;

            // rotate (|rv| == 1); mats entries are uniform scalar operands
            const float xh = fmaf(v0, mats[n*9+0], fmaf(v1, mats[n*9+3], v2 * mats[n*9+6]));
            const float yh = fmaf(v0, mats[n*9+1], fmaf(v1, mats[n*9+4], v2 * mats[n*9+7]));
            const float ct = fmaf(v0, mats[n*9+2], fmaf(v1, mats[n*9+5], v2 * mats[n*9+8]));

            // Legendre: P_l(ct) = ct^par * H(ct^2), parity-compressed
            const float ct2 = ct * ct;
            float v = coeffs[n*PLEN + par + 8];
            v = fmaf(v, ct2, coeffs[n*PLEN + par + 6]);
            v = fmaf(v, ct2, coeffs[n*PLEN + par + 4]);
            v = fmaf(v, ct2, coeffs[n*PLEN + par + 2]);
            v = fmaf(v, ct2, coeffs[n*PLEN + par + 0]);
            if (par) v *= ct;             // uniform branch

            // Re[(xh+i*yh)^d]: uniform trip count (d==1 -> zero iterations)
            float R = xh;
            if (d > 1) {
                const float ss  = fmaf(yh, yh, xh * xh);
                const float m2x = xh + xh;
                float Rm2 = 1.0f, Rm1 = xh;
                for (int k = 2; k <= d; ++k) {
                    const float Rk = fmaf(m2x, Rm1, -(ss * Rm2));
                    Rm2 = Rm1;
                    Rm1 = Rk;
                }
                R = Rm1;
            }
            float cs = cscale[n];
            if (par) cs = -cs;            // fold (-1)^deg, uniform

            const float al = __builtin_amdgcn_exp2f((float)(d * (d + 1)) * tc);

            // bank = (lane + 2n) % 32 -> <=2-way across 64 lanes (free)
            row[2 * n + 0] = al * (y0n[n] * v);
            row[2 * n + 1] = al * (cs * R);
        }
    };

    // ---- stream one tile from LDS buffer `buf` to HBM (NT, full lines) ----
    auto store_tile = [&](int it, int buf) {
        f32x4* outp = reinterpret_cast<f32x4*>(out + (size_t)BB[it] * 64);
#pragma unroll
        for (int p = 0; p < 2; ++p) {     // 1024 chunks / 512 threads
            const int c  = p * 512 + t;   // chunk index in tile
            const int r  = c >> 4;        // source LDS row
            const int c4 = (c & 15) * 4;  // dword column
            const float* src = &lds[buf][r * ROWD + c4];
            f32x4 o = { src[0], src[1], src[2], src[3] };
            __builtin_nontemporal_store(o, outp + c);
        }
    };

    // ---- pipeline: store(T_i) || compute(T_{i+1}), one barrier per phase ----
    compute_tile(0, 0);
    __syncthreads();
#pragma unroll
    for (int it = 0; it < NTILE; ++it) {
        store_tile(it, it & 1);                       // issued first: drains in bg
        if (it + 1 < NTILE) {
            compute_tile(it + 1, (it + 1) & 1);       // VALU overlaps store drain
            __syncthreads();                          // next buf ready; prev fully read
        }
    }
}

extern "C" void kernel_launch(void* const* d_in, const int* in_sizes, int n_in,
                              void* d_out, int out_size, void* d_ws, size_t ws_size,
                              hipStream_t stream) {
    const float* vec    = (const float*)d_in[0];
    const float* rough  = (const float*)d_in[1];
    const float* mats   = (const float*)d_in[2];
    const float* coeffs = (const float*)d_in[3];
    const float* cscale = (const float*)d_in[4];
    const float* y0n    = (const float*)d_in[5];
    const int*   degs   = (const int*)d_in[6];
    float* out = (float*)d_out;

    const int B = in_sizes[1];            // roughness element count (262144)
    const int block = 512;                // 8 waves; 4 tiles of 64 directions
    const int grid = B / (64 * NTILE);    // 1024 blocks -> 4/CU, all resident

    randish_kernel<<<grid, block, 0, stream>>>(vec, rough, mats, coeffs, cscale,
                                               y0n, degs, out, B);
}

// Round 14
// 21.640 us; speedup vs baseline: 1.0016x; 1.0016x over previous
//
#include <hip/hip_runtime.h>
#include <math.h>

// RandISH, cooperative-tile layout v5: v4 + LDS-only barriers (stores drain
// across barriers).
//   out[b, 2n+0] = Al(deg_n, r_b) * y0_norm[n] * P_l(ct)
//   out[b, 2n+1] = Al * cscale[n] * (-1)^deg * Re[(rx + i*ry)^deg]
// rv = vec[b] @ M[n]; rotation preserves |vec|=1 -> no normalization.
//
// KEY CHANGE vs v4: __syncthreads() compiles to `s_waitcnt vmcnt(0)
// lgkmcnt(0); s_barrier` -- every phase barrier waited for the previous
// tile's NT stores to COMPLETE IN HBM, serializing store-drain with the
// next compute phase (the m97 barrier-drain stall). The inter-phase
// ordering only needs LDS visibility: store data is consumed from VGPRs at
// issue. So we barrier with `s_waitcnt lgkmcnt(0)` + raw s_barrier only;
// NT stores stay in flight across phases and drain in the background.
//
// Structure (from v4): block = 512 threads = 8 waves, FOUR 64-direction
// tiles, two LDS buffers [64][65] (odd stride -> <=2-way banks = free),
// 33.3 KB -> 4 blocks/CU = 32 waves/CU, all 1024 blocks resident.
//   lane (0..63) = direction b         -> coalesced input loads
//   wave w (0..7) = bases n=4w..4w+3   -> deg/mats/coeffs WAVE-UNIFORM
//     (readfirstlane-forced SGPR; Re[z^d] recurrence runs deg-1 real
//      iterations, ~54% run zero).
// Store: consecutive threads -> consecutive 16B -> full 128B lines, NT.
//
// Re[z^d]: R_k = 2x R_{k-1} - (x^2+y^2) R_{k-2},  R_0=1, R_1=x.
// Al = exp2(-0.5*log2e*d(d+1)*(r+eps))  (0.5/(1/(r+e)+e) ~= 0.5(r+e), 1e-8).

#define NBASIS 32
#define PLEN 10
#define EPSV 1e-8f
#define LOG2E 1.44269504088896340736f
#define ROWD 65    // LDS row stride in dwords (odd -> conflict-free)
#define NTILE 4    // tiles per block

// LDS-only barrier: ds ops ordered, NT stores free-run across it.
#define BAR_LDS()  do {                                           \
    asm volatile("s_waitcnt lgkmcnt(0)" ::: "memory");            \
    __builtin_amdgcn_s_barrier();                                 \
} while (0)

typedef float f32x4 __attribute__((ext_vector_type(4)));

__global__ __launch_bounds__(512) void randish_kernel(
    const float* __restrict__ vec,        // (B,3)
    const float* __restrict__ rough,      // (B,)
    const float* __restrict__ mats,       // (32,3,3)
    const float* __restrict__ coeffs,     // (32,10) increasing power
    const float* __restrict__ cscale,     // (32,)
    const float* __restrict__ y0n,        // (32,)
    const int*   __restrict__ degs,       // (32,)
    float* __restrict__ out,              // (B,64)
    int B)
{
    __shared__ float lds[2][64 * ROWD];   // 33.3 KB -> 4 blocks/CU

    const int t    = threadIdx.x;         // 0..511
    const int lane = t & 63;              // direction within tile
    const int w    = t >> 6;              // wave id 0..7

    // ---- prefetch ALL tiles' inputs (independent loads, one window) ----
    float V0[NTILE], V1[NTILE], V2[NTILE], TC[NTILE];
    int   BB[NTILE];
#pragma unroll
    for (int it = 0; it < NTILE; ++it) {
        const int b0 = (blockIdx.x * NTILE + it) * 64;
        const int b  = b0 + lane;         // B % (64*NTILE) == 0 -> in range
        BB[it] = b0;
        V0[it] = vec[b * 3 + 0];
        V1[it] = vec[b * 3 + 1];
        V2[it] = vec[b * 3 + 2];
        // Al = exp2( d*(d+1) * tc ),  tc = -0.5*log2e*(r+eps)
        TC[it] = (rough[b] + EPSV) * (-0.5f * LOG2E);
    }

    // ---- compute one tile into LDS buffer `buf` ----
    auto compute_tile = [&](int it, int buf) {
        const float v0 = V0[it], v1 = V1[it], v2 = V2[it], tc = TC[it];
        float* row = &lds[buf][lane * ROWD];
#pragma unroll
        for (int j = 0; j < 4; ++j) {
            // n and all derived per-n data are wave-uniform -> SGPRs
            const int n = __builtin_amdgcn_readfirstlane(4 * w + j);
            const int d = __builtin_amdgcn_readfirstlane(degs[n]);
            const int par = d & 1;

            // rotate (|rv| == 1); mats entries are uniform scalar operands
            const float xh = fmaf(v0, mats[n*9+0], fmaf(v1, mats[n*9+3], v2 * mats[n*9+6]));
            const float yh = fmaf(v0, mats[n*9+1], fmaf(v1, mats[n*9+4], v2 * mats[n*9+7]));
            const float ct = fmaf(v0, mats[n*9+2], fmaf(v1, mats[n*9+5], v2 * mats[n*9+8]));

            // Legendre: P_l(ct) = ct^par * H(ct^2), parity-compressed
            const float ct2 = ct * ct;
            float v = coeffs[n*PLEN + par + 8];
            v = fmaf(v, ct2, coeffs[n*PLEN + par + 6]);
            v = fmaf(v, ct2, coeffs[n*PLEN + par + 4]);
            v = fmaf(v, ct2, coeffs[n*PLEN + par + 2]);
            v = fmaf(v, ct2, coeffs[n*PLEN + par + 0]);
            if (par) v *= ct;             // uniform branch

            // Re[(xh+i*yh)^d]: uniform trip count (d==1 -> zero iterations)
            float R = xh;
            if (d > 1) {
                const float ss  = fmaf(yh, yh, xh * xh);
                const float m2x = xh + xh;
                float Rm2 = 1.0f, Rm1 = xh;
                for (int k = 2; k <= d; ++k) {
                    const float Rk = fmaf(m2x, Rm1, -(ss * Rm2));
                    Rm2 = Rm1;
                    Rm1 = Rk;
                }
                R = Rm1;
            }
            float cs = cscale[n];
            if (par) cs = -cs;            // fold (-1)^deg, uniform

            const float al = __builtin_amdgcn_exp2f((float)(d * (d + 1)) * tc);

            // bank = (lane + 2n) % 32 -> <=2-way across 64 lanes (free)
            row[2 * n + 0] = al * (y0n[n] * v);
            row[2 * n + 1] = al * (cs * R);
        }
    };

    // ---- stream one tile from LDS buffer `buf` to HBM (NT, full lines) ----
    auto store_tile = [&](int it, int buf) {
        f32x4* outp = reinterpret_cast<f32x4*>(out + (size_t)BB[it] * 64);
#pragma unroll
        for (int p = 0; p < 2; ++p) {     // 1024 chunks / 512 threads
            const int c  = p * 512 + t;   // chunk index in tile
            const int r  = c >> 4;        // source LDS row
            const int c4 = (c & 15) * 4;  // dword column
            const float* src = &lds[buf][r * ROWD + c4];
            f32x4 o = { src[0], src[1], src[2], src[3] };
            __builtin_nontemporal_store(o, outp + c);
        }
    };

    // ---- pipeline: store(T_i) || compute(T_{i+1}); LDS-only barriers ----
    compute_tile(0, 0);
    BAR_LDS();
#pragma unroll
    for (int it = 0; it < NTILE; ++it) {
        store_tile(it, it & 1);                       // NT stores drain in bg
        if (it + 1 < NTILE) {
            compute_tile(it + 1, (it + 1) & 1);       // VALU overlaps store drain
            BAR_LDS();                                // LDS ready; stores free-run
        }
    }
}

extern "C" void kernel_launch(void* const* d_in, const int* in_sizes, int n_in,
                              void* d_out, int out_size, void* d_ws, size_t ws_size,
                              hipStream_t stream) {
    const float* vec    = (const float*)d_in[0];
    const float* rough  = (const float*)d_in[1];
    const float* mats   = (const float*)d_in[2];
    const float* coeffs = (const float*)d_in[3];
    const float* cscale = (const float*)d_in[4];
    const float* y0n    = (const float*)d_in[5];
    const int*   degs   = (const int*)d_in[6];
    float* out = (float*)d_out;

    const int B = in_sizes[1];            // roughness element count (262144)
    const int block = 512;                // 8 waves; 4 tiles of 64 directions
    const int grid = B / (64 * NTILE);    // 1024 blocks -> 4/CU, all resident

    randish_kernel<<<grid, block, 0, stream>>>(vec, rough, mats, coeffs, cscale,
                                               y0n, degs, out, B);
}

// Round 15
// 20.647 us; speedup vs baseline: 1.0497x; 1.0481x over previous
//
#include <hip/hip_runtime.h>
#include <math.h>

// RandISH, cooperative-tile v6: R11 winning structure + LDS-only barriers
// + batched store-phase reads.
//   out[b, 2n+0] = Al(deg_n, r_b) * y0_norm[n] * P_l(ct)
//   out[b, 2n+1] = Al * cscale[n] * (-1)^deg * Re[(rx + i*ry)^deg]
// rv = vec[b] @ M[n]; rotation preserves |vec|=1 -> no normalization.
//
// Structure (R11, 20.5us): block = 256 threads = 4 waves, TWO 64-direction
// tiles back-to-back, single LDS buffer [64][65] (odd stride -> <=2-way
// banks = free), 16.6 KB -> grid 2048 = 8 blocks/CU = 32 waves/CU, all
// resident; cross-block TLP provides compute/store overlap (R12/R13's
// in-block dbuf at 4 blocks/CU was net-negative).
//   lane (0..63) = direction b          -> coalesced input loads
//   wave w (0..3) = bases n=8w..8w+7    -> deg/mats/coeffs WAVE-UNIFORM
//     (readfirstlane-forced SGPR; Re[z^d] recurrence runs deg-1 real
//      iterations, ~54% run zero).
//
// v6 deltas vs R11:
//  (a) __syncthreads() -> `s_waitcnt lgkmcnt(0)` + s_barrier. syncthreads
//      drains vmcnt(0) too, i.e. waits for NT stores to COMPLETE IN HBM
//      at every phase boundary; LDS visibility only needs lgkm. NT stores
//      now drain across barriers in the background.
//  (b) store phase: 4 ds_reads batched into regs (pipelined counted lgkm
//      waits), then 4 NT stores back-to-back (full 128B lines).
//
// Re[z^d]: R_k = 2x R_{k-1} - (x^2+y^2) R_{k-2},  R_0=1, R_1=x.
// Al = exp2(-0.5*log2e*d(d+1)*(r+eps))  (0.5/(1/(r+e)+e) ~= 0.5(r+e), 1e-8).

#define NBASIS 32
#define PLEN 10
#define EPSV 1e-8f
#define LOG2E 1.44269504088896340736f
#define ROWD 65    // LDS row stride in dwords (odd -> conflict-free)
#define NT 2       // tiles per block

// LDS-only barrier: ds ops ordered, NT stores free-run across it.
#define BAR_LDS()  do {                                           \
    asm volatile("s_waitcnt lgkmcnt(0)" ::: "memory");            \
    __builtin_amdgcn_s_barrier();                                 \
} while (0)

typedef float f32x4 __attribute__((ext_vector_type(4)));

__global__ __launch_bounds__(256) void randish_kernel(
    const float* __restrict__ vec,        // (B,3)
    const float* __restrict__ rough,      // (B,)
    const float* __restrict__ mats,       // (32,3,3)
    const float* __restrict__ coeffs,     // (32,10) increasing power
    const float* __restrict__ cscale,     // (32,)
    const float* __restrict__ y0n,        // (32,)
    const int*   __restrict__ degs,       // (32,)
    float* __restrict__ out,              // (B,64)
    int B)
{
    __shared__ float lds[64 * ROWD];      // 16.6 KB -> 8 blocks/CU (grid-capped)

    const int t    = threadIdx.x;         // 0..255
    const int lane = t & 63;              // direction within tile
    const int w    = t >> 6;              // wave id 0..3

    // ---- prefetch BOTH tiles' inputs (independent loads, one window) ----
    float V0[NT], V1[NT], V2[NT], TC[NT];
    int   BB[NT];
#pragma unroll
    for (int it = 0; it < NT; ++it) {
        const int b0 = (blockIdx.x * NT + it) * 64;
        const int b  = b0 + lane;         // B % (64*NT) == 0 -> in range
        BB[it] = b0;
        V0[it] = vec[b * 3 + 0];
        V1[it] = vec[b * 3 + 1];
        V2[it] = vec[b * 3 + 2];
        // Al = exp2( d*(d+1) * tc ),  tc = -0.5*log2e*(r+eps)
        TC[it] = (rough[b] + EPSV) * (-0.5f * LOG2E);
    }

    float* row = &lds[lane * ROWD];

#pragma unroll
    for (int it = 0; it < NT; ++it) {
        const float v0 = V0[it], v1 = V1[it], v2 = V2[it], tc = TC[it];

        // ---- compute tile into LDS ----
#pragma unroll
        for (int j = 0; j < 8; ++j) {
            // n and all derived per-n data are wave-uniform -> SGPRs
            const int n = __builtin_amdgcn_readfirstlane(8 * w + j);
            const int d = __builtin_amdgcn_readfirstlane(degs[n]);
            const int par = d & 1;

            // rotate (|rv| == 1); mats entries are uniform scalar operands
            const float xh = fmaf(v0, mats[n*9+0], fmaf(v1, mats[n*9+3], v2 * mats[n*9+6]));
            const float yh = fmaf(v0, mats[n*9+1], fmaf(v1, mats[n*9+4], v2 * mats[n*9+7]));
            const float ct = fmaf(v0, mats[n*9+2], fmaf(v1, mats[n*9+5], v2 * mats[n*9+8]));

            // Legendre: P_l(ct) = ct^par * H(ct^2), parity-compressed
            const float ct2 = ct * ct;
            float v = coeffs[n*PLEN + par + 8];
            v = fmaf(v, ct2, coeffs[n*PLEN + par + 6]);
            v = fmaf(v, ct2, coeffs[n*PLEN + par + 4]);
            v = fmaf(v, ct2, coeffs[n*PLEN + par + 2]);
            v = fmaf(v, ct2, coeffs[n*PLEN + par + 0]);
            if (par) v *= ct;             // uniform branch

            // Re[(xh+i*yh)^d]: uniform trip count (d==1 -> zero iterations)
            float R = xh;
            if (d > 1) {
                const float ss  = fmaf(yh, yh, xh * xh);
                const float m2x = xh + xh;
                float Rm2 = 1.0f, Rm1 = xh;
                for (int k = 2; k <= d; ++k) {
                    const float Rk = fmaf(m2x, Rm1, -(ss * Rm2));
                    Rm2 = Rm1;
                    Rm1 = Rk;
                }
                R = Rm1;
            }
            float cs = cscale[n];
            if (par) cs = -cs;            // fold (-1)^deg, uniform

            const float al = __builtin_amdgcn_exp2f((float)(d * (d + 1)) * tc);

            // bank = (lane + 2n) % 32 -> <=2-way across 64 lanes (free)
            row[2 * n + 0] = al * (y0n[n] * v);
            row[2 * n + 1] = al * (cs * R);
        }

        BAR_LDS();                        // LDS writes visible; stores free-run

        // ---- store tile: batch 4 ds_reads, then 4 NT stores ----
        // 1024 dwordx4 chunks/tile, 4 per thread; consecutive threads ->
        // consecutive 16B -> full 128B lines (NT streaming path)
        f32x4 o[4];
#pragma unroll
        for (int p = 0; p < 4; ++p) {
            const int c  = p * 256 + t;   // chunk index in tile
            const int r  = c >> 4;        // source LDS row
            const int c4 = (c & 15) * 4;  // dword column
            const float* src = &lds[r * ROWD + c4];
            o[p] = f32x4{ src[0], src[1], src[2], src[3] };
        }
        f32x4* outp = reinterpret_cast<f32x4*>(out + (size_t)BB[it] * 64);
#pragma unroll
        for (int p = 0; p < 4; ++p)
            __builtin_nontemporal_store(o[p], outp + p * 256 + t);

        if (it + 1 < NT) BAR_LDS();       // reads done (lgkm) before overwrite
    }
}

extern "C" void kernel_launch(void* const* d_in, const int* in_sizes, int n_in,
                              void* d_out, int out_size, void* d_ws, size_t ws_size,
                              hipStream_t stream) {
    const float* vec    = (const float*)d_in[0];
    const float* rough  = (const float*)d_in[1];
    const float* mats   = (const float*)d_in[2];
    const float* coeffs = (const float*)d_in[3];
    const float* cscale = (const float*)d_in[4];
    const float* y0n    = (const float*)d_in[5];
    const int*   degs   = (const int*)d_in[6];
    float* out = (float*)d_out;

    const int B = in_sizes[1];            // roughness element count (262144)
    const int block = 256;                // 4 waves; 2 tiles of 64 directions
    const int grid = B / (64 * NT);       // 2048 blocks -> 8/CU, all resident

    randish_kernel<<<grid, block, 0, stream>>>(vec, rough, mats, coeffs, cscale,
                                               y0n, degs, out, B);
}